// Round 8
// baseline (742.509 us; speedup 1.0000x reference)
//
#include <hip/hip_runtime.h>
#include <math.h>

// Problem dims
#define TB 16   // batch (tasks)
#define TT 16   // train steps
#define LL 128  // test length
#define XX 256  // x dim
#define HH 512  // hidden
#define YY 256  // y dim

#define PW 584  // phase-2 act row pitch (>= 576 + pad)

typedef unsigned long long u64;

// ---------------------------------------------------------------------------
// Cross-block communication primitives.
// WRITES: relaxed agent-scope atomic EXCHANGE (RMW) — executes at the device
//   coherent point (same as the barrier fetch_add), unlike a relaxed atomic
//   store which may linger dirty in the writer XCD's L2 (the R5/R7 race).
// READS: relaxed agent-scope atomic loads (bypass local caches).
// ---------------------------------------------------------------------------
__device__ __forceinline__ void axg(float* p, float v) {
    (void)__hip_atomic_exchange(p, v, __ATOMIC_RELAXED, __HIP_MEMORY_SCOPE_AGENT);
}
__device__ __forceinline__ float ald(const float* p) {
    return __hip_atomic_load(p, __ATOMIC_RELAXED, __HIP_MEMORY_SCOPE_AGENT);
}
__device__ __forceinline__ u64 ald8(const u64* p) {
    return __hip_atomic_load(p, __ATOMIC_RELAXED, __HIP_MEMORY_SCOPE_AGENT);
}

// ---------------------------------------------------------------------------
// Counter-poll barrier (16 blocks/task): arrive = fetch_add on tb[0];
// waiters poll the counter itself. Monotonic. __syncthreads before arrive
// drains vmcnt for all waves (exchange-writes ack'd at the coherent point).
// ---------------------------------------------------------------------------
__device__ __forceinline__ void barrier_arrive(unsigned* tb) {
    __hip_atomic_fetch_add(&tb[0], 1u, __ATOMIC_RELAXED, __HIP_MEMORY_SCOPE_AGENT);
}
__device__ __forceinline__ void barrier_wait(unsigned* tb, unsigned n) {
    while (__hip_atomic_load(&tb[0], __ATOMIC_RELAXED,
                             __HIP_MEMORY_SCOPE_AGENT) < n * 16u)
        __builtin_amdgcn_s_sleep(1);
}

// Sum 16 per-block partials -> s_c[s] = lr*(c[s]+plus1). 64-bit atomic loads.
__device__ __forceinline__ void cload(const float* crd, float plus1, float lr,
                                      float* s_c) {
    const int tid = threadIdx.x;
    if (tid < 128) {
        const int s = tid >> 3, j = tid & 7;
        const u64 u = ald8((const u64*)(crd + s * 16) + j);
        float v = __uint_as_float((unsigned)(u & 0xffffffffu)) +
                  __uint_as_float((unsigned)(u >> 32));
        v += __shfl_xor(v, 1);
        v += __shfl_xor(v, 2);
        v += __shfl_xor(v, 4);
        if (j == 0) s_c[s] = lr * (v + plus1);
    }
}

// Partial dots of fresh slice (sout) against own LDS history rows s <= tmax.
__device__ __forceinline__ void partials32L(const float* hist, int tmax,
                                            float* cpw, int blk, const float* sout) {
    const int tid = threadIdx.x;
    const int s2 = tid >> 4, i = tid & 15;
    float pp = 0.f;
    const bool act = (s2 <= tmax);
    if (act) {
        pp = hist[s2 * 32 + 2 * i] * sout[2 * i] +
             hist[s2 * 32 + 2 * i + 1] * sout[2 * i + 1];
    }
    pp += __shfl_xor(pp, 1);
    pp += __shfl_xor(pp, 2);
    pp += __shfl_xor(pp, 4);
    pp += __shfl_xor(pp, 8);
    if (act && i == 0) axg(&cpw[s2 * 16 + blk], pp);
}

__device__ __forceinline__ void partials16L(const float* hist, int tmax,
                                            float* cpw, int blk, const float* sout) {
    const int tid = threadIdx.x;
    const int s2 = tid >> 4, i = tid & 15;
    float pp = 0.f;
    const bool act = (s2 <= tmax);
    if (act) pp = hist[s2 * 16 + i] * sout[i];
    pp += __shfl_xor(pp, 1);
    pp += __shfl_xor(pp, 2);
    pp += __shfl_xor(pp, 4);
    pp += __shfl_xor(pp, 8);
    if (act && i == 0) axg(&cpw[s2 * 16 + blk], pp);
}

// ---------------------------------------------------------------------------
// One phase-1 stage. MODE: 0=F2 1=F3 2=F4 3=B4 4=B3 5=B2(+h1_{t+1}).
// Weight slice prefetched to REGISTERS before the barrier wait; history in
// LDS; fresh vector + coefficient partials via agent atomics (IF).
// ---------------------------------------------------------------------------
template <int MODE>
__device__ __forceinline__ void do_stage(
    int t, unsigned n, float lr, int base, int base16, int blk,
    const float* __restrict__ M, const float* __restrict__ src,
    float* __restrict__ dst, float* __restrict__ dst2,
    const float* __restrict__ tyb, const float* __restrict__ tgb, float rbias,
    unsigned* __restrict__ tb, float* __restrict__ cw, float* __restrict__ crd,
    float* s_v, float* sp, float* sout, float* s_c,
    float* hcorr, float* hpart, float* hself,
    float* hD1v, float* hZ1v, float* sG1v)
{
    const int tid = threadIdx.x;
    constexpr int ROWS = (MODE == 2) ? 16 : 32;
    constexpr int G = 256 / ROWS;
    constexpr int KTOT = (MODE == 3) ? 256 : 512;
    constexpr int KPG = KTOT / G;
    constexpr int LD = (MODE == 2) ? YY : HH;

    const int r = tid & (ROWS - 1);
    const int j = tid / ROWS;

    // ---- weight prefetch (before barrier; overlaps the wait) ----
    const float* col = M + (j * KPG) * LD + r;
    float wreg[KPG];
    #pragma unroll
    for (int k = 0; k < KPG; ++k) wreg[k] = col[k * LD];

    // ---- wait for previous stage (all 16 blocks) ----
    if (tid == 0) barrier_wait(tb, n);
    __syncthreads();

    // ---- stage fresh vector + coefficients (IF reads, parallel) ----
    constexpr float P1 = (MODE == 0 || MODE == 1) ? 1.0f : 0.0f;
    cload(crd, P1, lr, s_c);
    constexpr int NF = (MODE == 3) ? YY : HH;
    if (tid < (NF >> 1)) ((u64*)s_v)[tid] = ald8((const u64*)src + tid);
    __syncthreads();

    // ---- matvec: registers x LDS ----
    float a = 0.f;
    const float* vv = s_v + j * KPG;
    #pragma unroll
    for (int k = 0; k < KPG; ++k) a += wreg[k] * vv[k];
    const int lane = tid & 63, w = tid >> 6;
    float sres = 0.f;
    if constexpr (ROWS == 32) {
        a += __shfl_xor(a, 32);
        if (lane < 32) sp[w * 32 + lane] = a;
        __syncthreads();
        if (tid < 32) sres = sp[tid] + sp[32 + tid] + sp[64 + tid] + sp[96 + tid];
    } else {
        a += __shfl_xor(a, 16);
        a += __shfl_xor(a, 32);
        if (lane < 16) sp[w * 16 + lane] = a;
        __syncthreads();
        if (tid < 16) sres = sp[tid] + sp[16 + tid] + sp[32 + tid] + sp[48 + tid];
    }

    // ---- epilogue (LDS history only) ----
    if (tid < ROWS) {
        float corr = 0.f;
        for (int s = 0; s < t; ++s) corr += hcorr[s * ROWS + tid] * s_c[s];
        if constexpr (MODE == 5) {
            const float dz = (sres - corr) * ((hcorr[t * 32 + tid] > 0.f) ? 1.f : 0.f);
            axg(dst + t * HH + base + tid, dz);
            hD1v[t * 32 + tid] = dz;
            if (t + 1 < TT) {
                float cr = dz * sG1v[t * 16 + (t + 1)];
                for (int s = 0; s < t; ++s)
                    cr += hD1v[s * 32 + tid] * sG1v[s * 16 + (t + 1)];
                const float h1n = fmaxf(hZ1v[(t + 1) * 32 + tid] - lr * cr, 0.f);
                axg(dst2 + (t + 1) * HH + base + tid, h1n);
                hself[(t + 1) * 32 + tid] = h1n;
                sout[tid] = h1n;
            }
        } else {
            float v;
            if constexpr (MODE == 0)
                v = fmaxf(sres + rbias - corr, 0.f);
            else if constexpr (MODE == 1)
                v = fmaxf(sres + rbias - corr, 0.f) * tgb[t * HH + base + tid];
            else if constexpr (MODE == 2)
                v = (sres - corr - tyb[t * YY + base16 + tid]) * (2.0f / YY);
            else if constexpr (MODE == 3)
                v = (sres - corr) * tgb[t * HH + base + tid] *
                    ((hcorr[t * 32 + tid] > 0.f) ? 1.f : 0.f);
            else
                v = (sres - corr) * ((hcorr[t * 32 + tid] > 0.f) ? 1.f : 0.f);
            if constexpr (MODE == 2) axg(dst + t * YY + base16 + tid, v);
            else                     axg(dst + t * HH + base + tid, v);
            hself[t * ROWS + tid] = v;
            sout[tid] = v;
        }
    }
    __syncthreads();

    // ---- partials for next stage's coefficients ----
    const int tmax = (MODE == 5) ? ((t + 1 < TT) ? t : -1) : (t - 1);
    if constexpr (MODE == 2) partials16L(hpart, tmax, cw, blk, sout);
    else                     partials32L(hpart, tmax, cw, blk, sout);
    __syncthreads();   // drains exchange-writes (all waves)
    if (tid == 0) barrier_arrive(tb);
}

// ---------------------------------------------------------------------------
// Transpose W1..W4 (64x64 tiles), zero barrier flags, write inner_lr output.
// ---------------------------------------------------------------------------
__global__ __launch_bounds__(256) void k_tr(
    const float* __restrict__ W1, const float* __restrict__ W2,
    const float* __restrict__ W3, const float* __restrict__ W4,
    float* __restrict__ WT1, float* __restrict__ WT2,
    float* __restrict__ WT3, float* __restrict__ WT4,
    const float* __restrict__ loglr, float* __restrict__ out,
    unsigned* __restrict__ bars)
{
    const int tid = threadIdx.x;
    int bid = blockIdx.x;
    if (blockIdx.x == 0)
        (void)__hip_atomic_exchange(&bars[tid], 0u, __ATOMIC_RELAXED,
                                    __HIP_MEMORY_SCOPE_AGENT);
    if (blockIdx.x == 0 && tid == 0) out[2048] = expf(loglr[0]);

    const float* src; float* dst; int R, C;
    if (bid < 32)       { src = W1; dst = WT1; R = 512; C = 256; }
    else if (bid < 96)  { src = W2; dst = WT2; R = 512; C = 512; bid -= 32; }
    else if (bid < 160) { src = W3; dst = WT3; R = 512; C = 512; bid -= 96; }
    else                { src = W4; dst = WT4; R = 256; C = 512; bid -= 160; }
    const int tilesC = C >> 6;
    const int i0 = (bid / tilesC) * 64, j0 = (bid % tilesC) * 64;

    __shared__ float sm[64][65];
    #pragma unroll
    for (int rep = 0; rep < 16; ++rep) {
        const int flat = rep * 256 + tid;
        const int r = flat >> 6, c = flat & 63;
        sm[r][c] = src[(i0 + r) * C + j0 + c];
    }
    __syncthreads();
    #pragma unroll
    for (int rep = 0; rep < 16; ++rep) {
        const int flat = rep * 256 + tid;
        const int c = flat >> 6, r = flat & 63;
        dst[(j0 + c) * R + i0 + r] = sm[r][c];
    }
}

// ---------------------------------------------------------------------------
// Persistent inner loop. 256 blocks of 256; 16 blocks/task, 32 rows/block.
// ---------------------------------------------------------------------------
__global__ __launch_bounds__(256, 1) void k_inner(
    const float* __restrict__ tx, const float* __restrict__ ty, const float* __restrict__ tg,
    const float* __restrict__ b1v, const float* __restrict__ b2v, const float* __restrict__ b3v,
    const float* __restrict__ W2, const float* __restrict__ W3, const float* __restrict__ W4,
    const float* __restrict__ WT1, const float* __restrict__ WT2, const float* __restrict__ WT3,
    const float* __restrict__ WT4, const float* __restrict__ loglr,
    float* __restrict__ H1, float* __restrict__ H2, float* __restrict__ HG,
    float* __restrict__ D1, float* __restrict__ D2, float* __restrict__ D3, float* __restrict__ D4,
    float* __restrict__ cpart, unsigned* __restrict__ bars)
{
    const int tid = threadIdx.x;
    const int lane = tid & 63, w = tid >> 6;
    const int g = blockIdx.x;
    const int b = g >> 4;
    const int blk = ((g & 7) << 1) | ((g >> 3) & 1);   // XCD-local weight rows
    const int base = blk * 32, base16 = blk * 16;
    const float lr = expf(loglr[0]);
    unsigned* tb = bars + b * 16;

    const float* txb = tx + b * (TT * XX);
    const float* tyb = ty + b * (TT * YY);
    const float* tgb = tg + b * (TT * HH);
    float* H1b = H1 + b * (TT * HH);
    float* H2b = H2 + b * (TT * HH);
    float* HGb = HG + b * (TT * HH);
    float* D1b = D1 + b * (TT * HH);
    float* D2b = D2 + b * (TT * HH);
    float* D3b = D3 + b * (TT * HH);
    float* D4b = D4 + b * (TT * YY);
    float* cw  = cpart + b * 256;          // parity-0 partial buffer [16 s][16 blk]
    float* crd = cpart + 4096 + b * 256;   // parity-1

    __shared__ float s_x[16 * 260];  // P0 only
    __shared__ float spz[2176];      // P0 only
    __shared__ __align__(16) float s_v[HH];
    __shared__ float sp[128];
    __shared__ float sout[32];
    __shared__ float s_c[16];
    // Block-private history (own 32/16-row slices), LDS-resident:
    __shared__ float hH1[TT * 32], hH2[TT * 32], hHG[TT * 32];
    __shared__ float hD1[TT * 32], hD2[TT * 32], hD3[TT * 32];
    __shared__ float hD4[TT * 16];
    __shared__ float hZ1[TT * 32];
    __shared__ float sG1[TT * 16];

    const float rb2 = (tid < 32) ? b2v[base + tid] : 0.f;
    const float rb3 = (tid < 32) ? b3v[base + tid] : 0.f;

    // ---------------- P0: Z1base (LDS), G1 (LDS, replicated), H1[0] ----------
    {
        const float4* src4 = (const float4*)txb;   // 1024 float4
        #pragma unroll
        for (int q = 0; q < 4; ++q) {
            const int idx = q * 256 + tid;
            const int tt = idx >> 6, k4 = idx & 63;
            *(float4*)&s_x[tt * 260 + k4 * 4] = src4[idx];
        }
    }
    __syncthreads();
    {
        const int r = tid & 31, j = tid >> 5;
        float acc[16];
        #pragma unroll
        for (int tt = 0; tt < 16; ++tt) acc[tt] = 0.f;
        const float* col = WT1 + (j * 32) * HH + base + r;
        #pragma unroll 4
        for (int kk = 0; kk < 32; ++kk) {
            const float wv = col[kk * HH];
            const int k = j * 32 + kk;
            #pragma unroll
            for (int tt = 0; tt < 16; ++tt) acc[tt] += wv * s_x[tt * 260 + k];
        }
        #pragma unroll
        for (int tt = 0; tt < 16; ++tt) {
            float a = acc[tt] + __shfl_xor(acc[tt], 32);
            if (lane < 32) spz[w * 544 + lane * 17 + tt] = a;
        }
        __syncthreads();
        const int rr = tid & 31, tp = tid >> 5;
        #pragma unroll
        for (int q = 0; q < 2; ++q) {
            const int tt = tp * 2 + q;
            const int row = base + rr;
            float v = spz[rr * 17 + tt] + spz[544 + rr * 17 + tt] +
                      spz[1088 + rr * 17 + tt] + spz[1632 + rr * 17 + tt];
            v += b1v[row];
            hZ1[tt * 32 + rr] = v;
            if (tt == 0) {
                const float h = fmaxf(v, 0.f);
                hH1[rr] = h;
                axg(&H1b[row], h);
            }
        }
    }
    {   // Gram matrix, replicated per block
        const int ss = tid >> 4, uu = tid & 15;
        float a = 0.f;
        for (int k = 0; k < 256; ++k) a += s_x[ss * 260 + k] * s_x[uu * 260 + k];
        sG1[ss * 16 + uu] = a + 1.0f;
    }
    __syncthreads();   // drains exchange + orders LDS writes
    if (tid == 0) barrier_arrive(tb);

    // ---------------- Phase 1: 16 SGD steps x 6 stages ----------------
    unsigned n = 1;
    #pragma unroll 1
    for (int t = 0; t < TT; ++t) {
        do_stage<0>(t, n++, lr, base, base16, blk, WT2 + base, H1b + t * HH,
                    H2b, nullptr, tyb, tgb, rb2, tb, cw, crd,
                    s_v, sp, sout, s_c, hD2, hH2, hH2, hD1, hZ1, sG1);
        { float* tmp = cw; cw = crd; crd = tmp; }
        do_stage<1>(t, n++, lr, base, base16, blk, WT3 + base, H2b + t * HH,
                    HGb, nullptr, tyb, tgb, rb3, tb, cw, crd,
                    s_v, sp, sout, s_c, hD3, hHG, hHG, hD1, hZ1, sG1);
        { float* tmp = cw; cw = crd; crd = tmp; }
        do_stage<2>(t, n++, lr, base, base16, blk, WT4 + base16, HGb + t * HH,
                    D4b, nullptr, tyb, tgb, 0.f, tb, cw, crd,
                    s_v, sp, sout, s_c, hD4, hD4, hD4, hD1, hZ1, sG1);
        { float* tmp = cw; cw = crd; crd = tmp; }
        do_stage<3>(t, n++, lr, base, base16, blk, W4 + base, D4b + t * YY,
                    D3b, nullptr, tyb, tgb, 0.f, tb, cw, crd,
                    s_v, sp, sout, s_c, hHG, hD3, hD3, hD1, hZ1, sG1);
        { float* tmp = cw; cw = crd; crd = tmp; }
        do_stage<4>(t, n++, lr, base, base16, blk, W3 + base, D3b + t * HH,
                    D2b, nullptr, tyb, tgb, 0.f, tb, cw, crd,
                    s_v, sp, sout, s_c, hH2, hD2, hD2, hD1, hZ1, sG1);
        { float* tmp = cw; cw = crd; crd = tmp; }
        do_stage<5>(t, n++, lr, base, base16, blk, W2 + base, D2b + t * HH,
                    D1b, H1b, tyb, tgb, 0.f, tb, cw, crd,
                    s_v, sp, sout, s_c, hH1, hH1, hH1, hD1, hZ1, sG1);
        { float* tmp = cw; cw = crd; crd = tmp; }
    }
}

// ---------------------------------------------------------------------------
// Phase-2 fused layer (per block: 8 test rows, all OUT columns). NORMAL loads
// only — runs in its own dispatch after k_inner (dispatch-boundary coherence).
// out[l][n] = post( sum_k WT[k][n]*act[l][k] + sum_s Dj[s][n]*(-lr*ip[s][l]) )
// via extended-K: act cols [K,K+16) hold -lr*ip, W rows [K,K+16) hold Dj;
// cols [K+16,KE) zero.
// ---------------------------------------------------------------------------
template <int K, int OUT, bool RELU, bool BIAS, bool PLUSONE>
__device__ __forceinline__ void p2_layer(
    const float* __restrict__ WT,      // [K][OUT]
    const float* __restrict__ bias,    // [OUT] or null
    const float* __restrict__ Dj,      // [16][OUT]
    const float* __restrict__ Asrc,    // [16][K]
    float lr, float* sact, float* sactN, float* sWA)
{
    constexpr int KE = (K + 16 + 63) & ~63;
    constexpr int KPG = KE / 8;
    const int tid = threadIdx.x;

    // ---- stage A rows into LDS (vectorized normal loads) ----
    float* sA = sWA;   // [16][K] flat
    for (int i = tid; i < (16 * K) / 4; i += 256)
        ((float4*)sA)[i] = ((const float4*)Asrc)[i];
    __syncthreads();

    // ---- ip[s][l] -> sact[l][K+s] = -lr*(A_s . act_l + plus1) ----
    {
        const int p = tid >> 1, half = tid & 1;
        const int s = p >> 3, l = p & 7;
        const float4* av = (const float4*)(sA + s * K + half * (K / 2));
        const float4* xv = (const float4*)(sact + l * PW + half * (K / 2));
        float a = 0.f;
        for (int k = 0; k < K / 8; ++k) {
            const float4 u = av[k], x = xv[k];
            a += u.x * x.x + u.y * x.y + u.z * x.z + u.w * x.w;
        }
        a += __shfl_xor(a, 1);
        if (half == 0) sact[l * PW + K + s] = -lr * (a + (PLUSONE ? 1.f : 0.f));
    }
    __syncthreads();

    // ---- GEMM: threads = 32 n x 8 k-groups; acc over 8 l's ----
    float* sP = sWA;   // [8*32][9] partials (sA dead after ip step)
    const int r = tid & 31, j = tid >> 5;
    for (int nc = 0; nc < OUT / 32; ++nc) {
        const int n = nc * 32 + r;
        float wreg[KPG];
        if ((j + 1) * KPG <= K) {
            const float* col = WT + (long)(j * KPG) * OUT + n;
            #pragma unroll
            for (int kk = 0; kk < KPG; ++kk) wreg[kk] = col[(long)kk * OUT];
        } else {
            #pragma unroll
            for (int kk = 0; kk < KPG; ++kk) {
                const int k = j * KPG + kk;
                wreg[kk] = (k < K) ? WT[(long)k * OUT + n]
                         : (k < K + 16) ? Dj[(k - K) * OUT + n] : 0.f;
            }
        }
        float acc[8];
        #pragma unroll
        for (int l = 0; l < 8; ++l) acc[l] = 0.f;
        const float* xb = sact + j * KPG;
        #pragma unroll 4
        for (int kk = 0; kk < KPG; ++kk) {
            const float wv = wreg[kk];
            #pragma unroll
            for (int l = 0; l < 8; ++l) acc[l] += wv * xb[l * PW + kk];
        }
        __syncthreads();   // sP free (vs sA / previous reduce's reads)
        #pragma unroll
        for (int l = 0; l < 8; ++l) sP[(j * 32 + r) * 9 + l] = acc[l];
        __syncthreads();
        {
            const int rr = tid >> 3, ll = tid & 7;
            float v = 0.f;
            #pragma unroll
            for (int q = 0; q < 8; ++q) v += sP[(q * 32 + rr) * 9 + ll];
            const int nn = nc * 32 + rr;
            if (BIAS) v += bias[nn];
            if (RELU) v = fmaxf(v, 0.f);
            sactN[ll * PW + nn] = v;
        }
    }
    __syncthreads();
    // zero-pad cols [OUT+16, PW) of the output for the next consumer
    constexpr int ZC = PW - (OUT + 16);
    for (int f = tid; f < 8 * ZC; f += 256) {
        const int l = f / ZC, c = f - l * ZC;
        sactN[l * PW + OUT + 16 + c] = 0.f;
    }
    __syncthreads();
}

// ---------------------------------------------------------------------------
// Phase-2: test forward + loss, fully block-local. grid 256 blocks of 256:
// block = (task b, 8 test rows). No atomics, no cross-block communication.
// ---------------------------------------------------------------------------
__global__ __launch_bounds__(256, 1) void k_p2(
    const float* __restrict__ tx, const float* __restrict__ tex,
    const float* __restrict__ tey, const float* __restrict__ teg,
    const float* __restrict__ b1v, const float* __restrict__ b2v,
    const float* __restrict__ b3v,
    const float* __restrict__ WT1, const float* __restrict__ WT2,
    const float* __restrict__ WT3, const float* __restrict__ WT4,
    const float* __restrict__ H1, const float* __restrict__ H2,
    const float* __restrict__ HG,
    const float* __restrict__ D1, const float* __restrict__ D2,
    const float* __restrict__ D3, const float* __restrict__ D4,
    const float* __restrict__ loglr, float* __restrict__ outp)
{
    const int tid = threadIdx.x;
    const int b = blockIdx.x >> 4;
    const int l0 = (blockIdx.x & 15) * 8;
    const float lr = expf(loglr[0]);

    __shared__ __align__(16) float pool[17536];   // 70 KB
    float* a0  = pool;            // act buffers [8][PW]
    float* a1  = pool + 4672;
    float* sWA = pool + 9344;     // scratch: sA [16][512] / sP

    const float* txb = tx + b * (TT * XX);
    const float* H1b = H1 + b * (TT * HH);
    const float* H2b = H2 + b * (TT * HH);
    const float* HGb = HG + b * (TT * HH);
    const float* D1b = D1 + b * (TT * HH);
    const float* D2b = D2 + b * (TT * HH);
    const float* D3b = D3 + b * (TT * HH);
    const float* D4b = D4 + b * (TT * YY);

    // stage tex rows (zero-padded to PW)
    for (int f = tid; f < 8 * PW; f += 256) {
        const int l = f / PW, c = f - l * PW;
        a0[f] = (c < XX) ? tex[((long)b * LL + l0 + l) * XX + c] : 0.f;
    }
    __syncthreads();

    p2_layer<XX, HH, true, true, true>(WT1, b1v, D1b, txb, lr, a0, a1, sWA);
    p2_layer<HH, HH, true, true, true>(WT2, b2v, D2b, H1b, lr, a1, a0, sWA);
    p2_layer<HH, HH, true, true, true>(WT3, b3v, D3b, H2b, lr, a0, a1, sWA);

    // gate act3 with test_gate
    for (int f = tid; f < 8 * HH; f += 256) {
        const int l = f >> 9, k = f & 511;
        a1[l * PW + k] *= teg[((long)b * LL + l0 + l) * HH + k];
    }
    __syncthreads();

    p2_layer<HH, YY, false, false, false>(WT4, nullptr, D4b, HGb, lr, a1, a0, sWA);

    // logits out
    for (int f = tid; f < 8 * YY; f += 256) {
        const int l = f >> 8, y = f & 255;
        outp[4097 + ((long)(b * LL + l0 + l)) * YY + y] = a0[l * PW + y];
    }
    // loss + evaluation
    {
        const int l = tid >> 5, kk = tid & 31;
        float a = 0.f;
        #pragma unroll
        for (int jj = 0; jj < 8; ++jj) {
            const int y = kk * 8 + jj;
            const float d = a0[l * PW + y] -
                            tey[((long)b * LL + l0 + l) * YY + y];
            a += d * d;
        }
        a += __shfl_xor(a, 1);
        a += __shfl_xor(a, 2);
        a += __shfl_xor(a, 4);
        a += __shfl_xor(a, 8);
        a += __shfl_xor(a, 16);
        if (kk == 0) {
            const float v = a * (1.0f / YY);
            const int idx = b * LL + l0 + l;
            outp[idx] = v;
            outp[2049 + idx] = v;
        }
    }
}

// ---------------------------------------------------------------------------
extern "C" void kernel_launch(void* const* d_in, const int* in_sizes, int n_in,
                              void* d_out, int out_size, void* d_ws, size_t ws_size,
                              hipStream_t stream)
{
    const float* tx    = (const float*)d_in[0];   // train_x  [B][T][X]
    const float* ty    = (const float*)d_in[1];   // train_y  [B][T][Y]
    const float* tex   = (const float*)d_in[2];   // test_x   [B][L][X]
    const float* tey   = (const float*)d_in[3];   // test_y   [B][L][Y]
    const float* tg    = (const float*)d_in[4];   // train_gate [B][T][H]
    const float* teg   = (const float*)d_in[5];   // test_gate  [B][L][H]
    const float* W1    = (const float*)d_in[6];
    const float* b1    = (const float*)d_in[7];
    const float* W2    = (const float*)d_in[8];
    const float* b2    = (const float*)d_in[9];
    const float* W3    = (const float*)d_in[10];
    const float* b3    = (const float*)d_in[11];
    const float* W4    = (const float*)d_in[12];
    const float* loglr = (const float*)d_in[13];

    float* out = (float*)d_out;
    float* ws  = (float*)d_ws;

    // workspace layout (floats)
    float* H1     = ws + 135168;        // 131072
    float* H2     = ws + 266240;        // 131072
    float* HG     = ws + 397312;        // 131072
    float* D1     = ws + 528384;        // 131072
    float* D2     = ws + 659456;        // 131072
    float* D3     = ws + 790528;        // 131072
    float* D4     = ws + 921600;        // 65536
    float* ActA   = ws + 1024000;       // holds WT1..WT4
    float* WT1    = ActA;               // [256][512] = 131072
    float* WT2    = ActA + 131072;      // [512][512] = 262144
    float* WT3    = ActA + 393216;      // [512][512] = 262144
    float* WT4    = ActA + 655360;      // [512][256] = 131072
    float* cpart  = ws + 3121152;       // 2 x [16 tasks][16 s][16 blk] = 8192
    unsigned* bars = (unsigned*)(ws + 3129344);  // 16 tasks x 16 uints

    // Transpose weights, zero barriers, emit inner_lr.
    k_tr<<<192, 256, 0, stream>>>(W1, W2, W3, W4, WT1, WT2, WT3, WT4, loglr, out, bars);

    // 16-step MAML inner loop (persistent; exchange-write handoff).
    k_inner<<<TB * 16, 256, 0, stream>>>(tx, ty, tg, b1, b2, b3, W2, W3, W4,
                                         WT1, WT2, WT3, WT4, loglr,
                                         H1, H2, HG, D1, D2, D3, D4,
                                         cpart, bars);

    // Phase 2: test-set forward + loss, one block-local dispatch.
    k_p2<<<TB * 16, 256, 0, stream>>>(tx, tex, tey, teg, b1, b2, b3,
                                      WT1, WT2, WT3, WT4,
                                      H1, H2, HG, D1, D2, D3, D4,
                                      loglr, out);
}